// Round 5
// baseline (3840.074 us; speedup 1.0000x reference)
//
#include <hip/hip_runtime.h>

typedef unsigned int u32;
typedef unsigned short u16;
typedef unsigned long long u64;

#define NT 16384
#define LN7 1.9459101090932196f
#define ZWORDS 118784   // Tp 4096 + upT 114688 u64 words

__device__ __forceinline__ u32 f2bf(float f){
  u32 u = __float_as_uint(f);
  return (u + 0x7fffu + ((u >> 16) & 1u)) >> 16;   // RNE to bf16
}
__device__ __forceinline__ float bflo(u32 v){ return __uint_as_float(v << 16); }

__global__ __launch_bounds__(1024) void k_zero(u64* p){
  int i = blockIdx.x * 1024 + threadIdx.x;
  if (i < ZWORDS) p[i] = 0ull;
}

// ---- sync primitives (proven rounds 0/3/4) ----
__device__ __forceinline__ void st_dev(u64* p, u64 v){
  asm volatile("global_store_dwordx2 %0, %1, off sc0 sc1" :: "v"(p), "v"(v) : "memory");
}
__device__ __forceinline__ u64 ld_dev(const u64* p){
  u64 v;
  asm volatile("global_load_dwordx2 %0, %1, off sc0 sc1\n\ts_waitcnt vmcnt(0)"
               : "=v"(v) : "v"(p) : "memory");
  return v;
}
__device__ __forceinline__ u64 ld_l2(const u64* p){
  u64 v;
  asm volatile("global_load_dwordx2 %0, %1, off sc0\n\ts_waitcnt vmcnt(0)"
               : "=v"(v) : "v"(p) : "memory");
  return v;
}
__device__ __forceinline__ u64 ld_issue(const u64* p){
  u64 v;
  asm volatile("global_load_dwordx2 %0, %1, off sc0 sc1" : "=v"(v) : "v"(p));
  return v;
}

// ============================================================================
// k_pre: 256 blocks, 1024 rows/block. 8 lanes per row, 8 elems per lane.
// LN stats + wi logit via 8-lane shfl reduce; k/v GEMV via shfl-broadcast of
// x with per-lane acc[8] (outputs d in [8p, 8p+8)). Peak ~35 VGPR -> no spill.
// ============================================================================
__global__ __launch_bounds__(1024) void k_pre(
    const float* __restrict__ inp,
    const float* __restrict__ Wk, const float* __restrict__ Wv,
    const float* __restrict__ lning, const float* __restrict__ lninb,
    const float* __restrict__ wiw, const float* __restrict__ wib,
    u16* __restrict__ knb, u16* __restrict__ valb,
    float* __restrict__ lgA, float* __restrict__ rnA,
    float* __restrict__ lsePart)
{
  const int tid = threadIdx.x, blk = blockIdx.x;
  const int batch = blk >> 4, chunk = blk & 15;
  const int p = tid & 7;
  const int base8 = p << 3;
  const int gb = tid & 56;          // 8-lane group base (within wave)
  __shared__ float red[16][2];

  float run_m = -3.4e38f, run_s = 0.f;
  const float wib0 = wib[0];

  for (int sub = 0; sub < 8; ++sub){
    const int rw = (sub << 7) | (tid >> 3);
    const size_t row = ((size_t)batch << 14) | (size_t)((chunk << 10) | rw);
    float x8[8];
    {
      const float4* xp = (const float4*)(inp + row*64 + base8);
      float4 a = xp[0], b = xp[1];
      x8[0]=a.x; x8[1]=a.y; x8[2]=a.z; x8[3]=a.w;
      x8[4]=b.x; x8[5]=b.y; x8[6]=b.z; x8[7]=b.w;
    }
    float s1 = 0.f;
    #pragma unroll
    for (int i = 0; i < 8; ++i) s1 += x8[i];
    #pragma unroll
    for (int off = 1; off < 8; off <<= 1) s1 += __shfl_xor(s1, off, 64);
    const float mean = s1 * (1.f/64.f);
    float s2 = 0.f;
    #pragma unroll
    for (int i = 0; i < 8; ++i){ float d = x8[i]-mean; s2 += d*d; }
    #pragma unroll
    for (int off = 1; off < 8; off <<= 1) s2 += __shfl_xor(s2, off, 64);
    const float rstd = rsqrtf(s2*(1.f/64.f) + 1e-5f);
    float lgp = 0.f;
    #pragma unroll
    for (int i = 0; i < 8; ++i){
      x8[i] = (x8[i]-mean)*rstd*lning[base8+i] + lninb[base8+i];
      lgp += x8[i]*wiw[base8+i];
    }
    #pragma unroll
    for (int off = 1; off < 8; off <<= 1) lgp += __shfl_xor(lgp, off, 64);
    const float lg = lgp + wib0;
    if (p == 0) lgA[row] = lg;
    {
      float nm = fmaxf(run_m, lg);
      run_s = run_s*__expf(run_m-nm) + __expf(lg-nm);
      run_m = nm;
    }
    // ---- k GEMV ----
    {
      float acc[8] = {0.f,0.f,0.f,0.f,0.f,0.f,0.f,0.f};
      #pragma unroll
      for (int c = 0; c < 8; ++c){
        const int sl = gb | c;
        float v0 = __shfl(x8[0], sl, 64), v1 = __shfl(x8[1], sl, 64),
              v2 = __shfl(x8[2], sl, 64), v3 = __shfl(x8[3], sl, 64),
              v4 = __shfl(x8[4], sl, 64), v5 = __shfl(x8[5], sl, 64),
              v6 = __shfl(x8[6], sl, 64), v7 = __shfl(x8[7], sl, 64);
        #pragma unroll
        for (int o = 0; o < 8; ++o){
          const float4 wa = *(const float4*)(Wk + (base8+o)*64 + c*8);
          const float4 wb = *(const float4*)(Wk + (base8+o)*64 + c*8 + 4);
          acc[o] += v0*wa.x + v1*wa.y + v2*wa.z + v3*wa.w
                  + v4*wb.x + v5*wb.y + v6*wb.z + v7*wb.w;
        }
      }
      float ss = 0.f;
      #pragma unroll
      for (int o = 0; o < 8; ++o) ss += acc[o]*acc[o];
      #pragma unroll
      for (int off = 1; off < 8; off <<= 1) ss += __shfl_xor(ss, off, 64);
      if (p == 0) rnA[row] = 1.f / fmaxf(sqrtf(ss), 1e-12f);
      u32 kp[4];
      #pragma unroll
      for (int j = 0; j < 4; ++j) kp[j] = f2bf(acc[2*j]) | (f2bf(acc[2*j+1]) << 16);
      *(uint4*)(knb + row*64 + base8) = *(uint4*)kp;
    }
    // ---- val GEMV ----
    {
      float acc[8] = {0.f,0.f,0.f,0.f,0.f,0.f,0.f,0.f};
      #pragma unroll
      for (int c = 0; c < 8; ++c){
        const int sl = gb | c;
        float v0 = __shfl(x8[0], sl, 64), v1 = __shfl(x8[1], sl, 64),
              v2 = __shfl(x8[2], sl, 64), v3 = __shfl(x8[3], sl, 64),
              v4 = __shfl(x8[4], sl, 64), v5 = __shfl(x8[5], sl, 64),
              v6 = __shfl(x8[6], sl, 64), v7 = __shfl(x8[7], sl, 64);
        #pragma unroll
        for (int o = 0; o < 8; ++o){
          const float4 wa = *(const float4*)(Wv + (base8+o)*64 + c*8);
          const float4 wb = *(const float4*)(Wv + (base8+o)*64 + c*8 + 4);
          acc[o] += v0*wa.x + v1*wa.y + v2*wa.z + v3*wa.w
                  + v4*wb.x + v5*wb.y + v6*wb.z + v7*wb.w;
        }
      }
      u32 kp[4];
      #pragma unroll
      for (int j = 0; j < 4; ++j) kp[j] = f2bf(acc[2*j]) | (f2bf(acc[2*j+1]) << 16);
      *(uint4*)(valb + row*64 + base8) = *(uint4*)kp;
    }
  }
  // ---- block LSE over 1024 rows (leader lanes only) ----
  if (p != 0){ run_m = -3.4e38f; run_s = 0.f; }
  #pragma unroll
  for (int off = 1; off < 64; off <<= 1){
    float om = __shfl_xor(run_m, off, 64);
    float os = __shfl_xor(run_s, off, 64);
    float nm = fmaxf(run_m, om);
    run_s = run_s*__expf(run_m-nm) + os*__expf(om-nm);
    run_m = nm;
  }
  if ((tid & 63) == 0){ red[tid>>6][0] = run_m; red[tid>>6][1] = run_s; }
  __syncthreads();
  if (tid == 0){
    float M = red[0][0];
    for (int w = 1; w < 16; ++w) M = fmaxf(M, red[w][0]);
    float S = 0.f;
    for (int w = 0; w < 16; ++w) S += __expf(red[w][0]-M)*red[w][1];
    lsePart[blk*2+0] = M;
    lsePart[blk*2+1] = S;
  }
}

// ============================================================================
// k_mesh: 256 blocks = 16 batches x 16 parties; 1024 rows/block, 1 row/thread.
// Per-row state ec[7]/pb[7]/aR/rse5 in registers (~55 live peak, fits 64).
// 16-party device-scope tagged sync (round-0 proven) + bounded L2 fast path.
// ============================================================================
__global__ __launch_bounds__(1024) void k_mesh(
    const float* __restrict__ noise, const float* __restrict__ mu,
    const float* __restrict__ sigma, const float* __restrict__ Wq,
    const float* __restrict__ gwih, const float* __restrict__ gwhh,
    const float* __restrict__ gbih, const float* __restrict__ gbhh,
    const float* __restrict__ fc1w, const float* __restrict__ fc1b,
    const float* __restrict__ fc2w, const float* __restrict__ fc2b,
    const float* __restrict__ lnslg, const float* __restrict__ lnslb,
    const float* __restrict__ lnffg, const float* __restrict__ lnffb,
    const float* __restrict__ wsw, const float* __restrict__ wsb,
    const u16* __restrict__ knb, const u16* __restrict__ valb,
    const float* __restrict__ lgA, const float* __restrict__ rnA,
    const float* __restrict__ lsePart,
    u64* Tp, u64* upT, float* out)
{
  const int tid = threadIdx.x;
  const int blk = blockIdx.x;
  // 16 parties of a batch share blk%8 -> same XCD under round-robin dispatch
  const int batch = (blk & 7) | ((blk >> 7) << 3);
  const int party = (blk >> 3) & 15;
  const int bp    = (batch << 4) | party;
  const int rbase = party << 10;

  __shared__ float Sl[7][64], Qn[7][64], Qt[7][64], Sst[7][64];
  __shared__ float Gx[7][192], Gh[7][192], H1[7][128];
  __shared__ float uacc[16][7][64];
  __shared__ float red[16][8];
  __shared__ float pol[16][8];
  __shared__ float vh[6][8], evT[6][8], logb[8], mxp[8], vw[8], rt[8];
  __shared__ float sS[2];

  float* ab = out + 7168 + (size_t)batch * 7 * NT;

  u32 bstep = 0;
  int tbuf = 0;
  int fastTries = 32, failcnt = 0;

  // mode 0: fwd step t; mode 1: G-sum; mode 2: bwd step t
  auto redshare = [&](float* part, int mode, int t){
    #pragma unroll
    for (int off = 32; off > 0; off >>= 1)
      #pragma unroll
      for (int s = 0; s < 7; ++s) part[s] += __shfl_xor(part[s], off, 64);
    if ((tid & 63) == 0){
      const int w = tid >> 6;
      #pragma unroll
      for (int s = 0; s < 7; ++s) red[w][s] = part[s];
    }
    __syncthreads();
    ++bstep;
    if (tid < 7){
      float p = 0.f;
      #pragma unroll
      for (int w = 0; w < 16; ++w) p += red[w][tid];
      u64 word = ((u64)bstep << 32) | (u64)__float_as_uint(p);
      st_dev(&Tp[(tbuf << 11) + bp*8 + tid], word);
    }
    if (tid < 128){
      const int w = tid >> 3, j0 = tid & 7;
      const int j = (j0 == 7) ? 0 : j0;
      const u64* src = &Tp[(tbuf << 11) + ((batch << 4) + w)*8 + j];
      u64 v; bool got = false;
      for (int k = 0; k < fastTries; ++k){
        v = ld_l2(src);
        if (__all((u32)(v >> 32) == bstep)){ got = true; break; }
      }
      if (!got){
        do { v = ld_dev(src); } while (!__all((u32)(v >> 32) == bstep));
        if (++failcnt >= 4) fastTries = 0;
      }
      if (j0 < 7) pol[w][j0] = __uint_as_float((u32)v);
    }
    __syncthreads();
    if (tid == 0){
      float T7[7];
      for (int s = 0; s < 7; ++s){
        float T = pol[0][s];
        for (int w = 1; w < 16; ++w) T += pol[w][s];
        T7[s] = T;
      }
      if (mode == 0){
        for (int s = 0; s < 7; ++s) vh[t][s] = logb[s] + mxp[t] - __logf(T7[s]);
        if (t < 5){
          float mxn = vh[t][0];
          for (int s = 1; s < 7; ++s) mxn = fmaxf(mxn, vh[t][s]);
          mxp[t+1] = mxn;
          for (int s = 0; s < 7; ++s) evT[t][s] = __expf(vh[t][s] - mxn);
        } else {
          for (int s = 0; s < 7; ++s) evT[5][s] = __expf(vh[5][s] - mxp[5]);
        }
      } else if (mode == 1){
        for (int s = 0; s < 7; ++s){
          vw[s] = T7[s] * __expf(vh[5][s] - logb[s] - mxp[5]);
          rt[s] = __expf(vh[4][s] - mxp[5]);
        }
      } else {
        for (int s = 0; s < 7; ++s){
          vw[s] = -T7[s] * __expf(vh[t-1][s] - logb[s] - mxp[t-1]);
          rt[s] = __expf(vh[t-2][s] - mxp[t-1]);
        }
      }
    }
    tbuf ^= 1;
    __syncthreads();
  };

  // ---- init: combine batch LSE; per-row aR in a register ----
  if (tid == 0){
    float M = lsePart[batch*32];
    for (int w = 1; w < 16; ++w) M = fmaxf(M, lsePart[batch*32 + 2*w]);
    float S = 0.f;
    for (int w = 0; w < 16; ++w)
      S += __expf(lsePart[batch*32 + 2*w] - M) * lsePart[batch*32 + 2*w + 1];
    sS[0] = M + __logf(S);
  }
  __syncthreads();
  const float LSE = sS[0];
  const size_t gr = ((size_t)batch << 14) | (size_t)(rbase | tid);
  const float aR = __expf(lgA[gr] - LSE + LN7);

  float ec[7], pb[7], rse5 = 0.f;

  for (int it = 0; it < 3; ++it){
    // ---- prologue: slots -> sn, logb, q, qn ----
    if (tid < 448){
      float sl;
      if (it == 0){
        const int d = tid & 63;
        sl = mu[d] + (fabsf(sigma[d]) + 1e-8f) * noise[batch*448 + tid];
      } else sl = Sst[tid>>6][tid&63];
      Sl[tid>>6][tid&63] = sl;
    }
    if (tid < 8) vh[5][tid] = 0.f;
    __syncthreads();
    if (tid < 7){
      float m2 = 0.f;
      for (int d = 0; d < 64; ++d) m2 += Sl[tid][d];
      m2 *= (1.f/64.f);
      float v2 = 0.f;
      for (int d = 0; d < 64; ++d){ float dd = Sl[tid][d]-m2; v2 += dd*dd; }
      v2 *= (1.f/64.f);
      float rs2 = rsqrtf(v2 + 1e-5f);
      float lgq = wsb[0];
      for (int d = 0; d < 64; ++d){
        float s = (Sl[tid][d]-m2)*rs2*lnslg[d] + lnslb[d];
        Qt[tid][d] = s;
        lgq += s*wsw[d];
      }
      red[0][tid] = lgq;
    }
    __syncthreads();
    if (tid == 0){
      float mx = red[0][0];
      for (int s = 1; s < 7; ++s) mx = fmaxf(mx, red[0][s]);
      float sm = 0.f;
      for (int s = 0; s < 7; ++s) sm += __expf(red[0][s]-mx);
      float lse = mx + __logf(sm);
      for (int s = 0; s < 7; ++s) logb[s] = red[0][s] - lse + LN7;
    }
    __syncthreads();
    if (tid < 448){
      const int s = tid >> 6, d = tid & 63;
      const float* wr = Wq + d*64;
      float acc2 = 0.f;
      #pragma unroll
      for (int dd = 0; dd < 64; ++dd) acc2 += Qt[s][dd]*wr[dd];
      Sl[s][d] = acc2;
    }
    __syncthreads();
    if (tid < 7){
      float sq = 0.f;
      for (int d = 0; d < 64; ++d) sq += Sl[tid][d]*Sl[tid][d];
      red[1][tid] = 1.f/fmaxf(sqrtf(sq), 1e-12f);
    }
    __syncthreads();
    if (tid < 448) Qn[tid>>6][tid&63] = Sl[tid>>6][tid&63]*red[1][tid>>6];
    __syncthreads();

    // ---- C build -> ec[s] = exp(-c), registers ----
    {
      float acc[7] = {0.f,0.f,0.f,0.f,0.f,0.f,0.f};
      const uint4* kr = (const uint4*)(knb + gr*64);
      #pragma unroll
      for (int q8 = 0; q8 < 8; ++q8){
        uint4 kv = kr[q8];
        float f0=bflo(kv.x), f1=__uint_as_float(kv.x & 0xffff0000u);
        float f2=bflo(kv.y), f3=__uint_as_float(kv.y & 0xffff0000u);
        float f4=bflo(kv.z), f5=__uint_as_float(kv.z & 0xffff0000u);
        float f6=bflo(kv.w), f7=__uint_as_float(kv.w & 0xffff0000u);
        const int d0 = q8*8;
        #pragma unroll
        for (int s = 0; s < 7; ++s){
          const float4 qa = *(const float4*)&Qn[s][d0];
          const float4 qb = *(const float4*)&Qn[s][d0+4];
          acc[s] += f0*qa.x + f1*qa.y + f2*qa.z + f3*qa.w
                  + f4*qb.x + f5*qb.y + f6*qb.z + f7*qb.w;
        }
      }
      const float rn_ = rnA[gr];
      #pragma unroll
      for (int s = 0; s < 7; ++s)
        ec[s] = __expf(-(1.f - rn_*acc[s]));
    }

    // ---- MESH: 4 grad passes (fwd5 + G + bwd5) + final fwd5 ----
    for (int m = 0; m < 5; ++m){
      if (tid == 0){
        float mxn = vh[5][0];
        for (int s = 1; s < 7; ++s) mxn = fmaxf(mxn, vh[5][s]);
        for (int s = 0; s < 7; ++s){ vh[0][s] = vh[5][s]; evT[0][s] = __expf(vh[5][s] - mxn); }
        mxp[1] = mxn;
      }
      __syncthreads();

      for (int t = 1; t <= 5; ++t){
        float evr[7];
        #pragma unroll
        for (int s = 0; s < 7; ++s) evr[s] = evT[t-1][s];
        float se = ec[0]*evr[0];
        #pragma unroll
        for (int s = 1; s < 7; ++s) se += ec[s]*evr[s];
        const float rse = 1.0f / se;
        if (t == 5) rse5 = rse;
        const float w = aR * rse;
        float t7[7];
        #pragma unroll
        for (int s = 0; s < 7; ++s) t7[s] = w * ec[s];
        redshare(t7, 0, t);
      }
      if (m == 4) break;

      // ---- G phase ----
      {
        const float mx5 = mxp[5];
        const float q = aR * rse5;
        const float base = __logf(aR) - mx5 + __logf(rse5);
        float gs[7];
        #pragma unroll
        for (int s = 0; s < 7; ++s){
          float at = q * ec[s] * evT[5][s];
          float lat = base + vh[5][s] + __logf(ec[s]);
          float G = -at * (lat + 1.f);
          pb[s] = G;
          gs[s] = G;
        }
        redshare(gs, 1, 0);
      }

      // ---- backward t = 5..1 ----
      for (int t = 5; t >= 1; --t){
        float vwr[7], rtr[7], evr[7];
        #pragma unroll
        for (int s = 0; s < 7; ++s){ vwr[s] = vw[s]; rtr[s] = rt[s]; evr[s] = evT[t-1][s]; }
        float se = ec[0]*evr[0];
        #pragma unroll
        for (int s = 1; s < 7; ++s) se += ec[s]*evr[s];
        const float rse = 1.0f / se;
        float ub = 0.f;
        if (t == 5){
          #pragma unroll
          for (int s = 0; s < 7; ++s) ub += pb[s];
        }
        float s1 = ec[0]*vwr[0];
        #pragma unroll
        for (int s = 1; s < 7; ++s) s1 += ec[s]*vwr[s];
        ub -= aR * rse * s1;
        const float u2 = ub * rse;
        const float ar_ = aR * rse;
        float ra[7];
        #pragma unroll
        for (int s = 0; s < 7; ++s){
          float er = ec[s] * rtr[s];
          ra[s] = u2 * er;
          pb[s] -= ar_ * vwr[s] * ec[s] + u2 * er;
        }
        if (t == 1){
          #pragma unroll
          for (int s = 0; s < 7; ++s) ec[s] = ec[s] * __expf(-pb[s]);   // c += pb
        }
        if (t > 1) redshare(ra, 2, t);
        else       __syncthreads();
      }
    } // m

    // ---- attn write ----
    {
      const int n = rbase | tid;
      const float wq = aR * rse5;
      #pragma unroll
      for (int s = 0; s < 7; ++s) ab[s*NT + n] = wq * ec[s] * evT[5][s];
    }
    __syncthreads();

    // ---- updates partial = attn^T @ val over this block's 1024 rows ----
    {
      const int w = tid >> 6, d = tid & 63;
      const int nb = rbase + (w << 6);
      float acc[7] = {0.f,0.f,0.f,0.f,0.f,0.f,0.f};
      const u16* vbp = valb + (((size_t)batch << 14) + (size_t)nb)*64 + d;
      #pragma unroll 1
      for (int i = 0; i < 64; i += 4){
        float4 a4[7];
        #pragma unroll
        for (int s = 0; s < 7; ++s) a4[s] = *(const float4*)(ab + s*NT + nb + i);
        #pragma unroll
        for (int j = 0; j < 4; ++j){
          float vv = bflo((u32)vbp[(size_t)(i+j)*64]);
          #pragma unroll
          for (int s = 0; s < 7; ++s) acc[s] += ((const float*)&a4[s])[j] * vv;
        }
      }
      #pragma unroll
      for (int s = 0; s < 7; ++s) uacc[w][s][d] = acc[s];
    }
    __syncthreads();

    // ---- cross-party sum of updates (16-party tagged sync) ----
    ++bstep;
    if (tid < 448){
      float u_ = 0.f;
      #pragma unroll
      for (int w = 0; w < 16; ++w) u_ += uacc[w][tid >> 6][tid & 63];
      u64 word = ((u64)bstep << 32) | (u64)__float_as_uint(u_);
      st_dev(&upT[(size_t)bp*448 + tid], word);
      const u64* base = &upT[(size_t)(batch << 4)*448 + tid];
      u64 vv[16];
      bool ok;
      do{
        #pragma unroll
        for (int p = 0; p < 16; ++p) vv[p] = ld_issue(base + p*448);
        asm volatile("s_waitcnt vmcnt(0)"
          : "+v"(vv[0]),"+v"(vv[1]),"+v"(vv[2]),"+v"(vv[3]),
            "+v"(vv[4]),"+v"(vv[5]),"+v"(vv[6]),"+v"(vv[7]),
            "+v"(vv[8]),"+v"(vv[9]),"+v"(vv[10]),"+v"(vv[11]),
            "+v"(vv[12]),"+v"(vv[13]),"+v"(vv[14]),"+v"(vv[15])
          :: "memory");
        ok = true;
        #pragma unroll
        for (int p = 0; p < 16; ++p) ok = ok && ((u32)(vv[p] >> 32) == bstep);
      } while (!__all(ok));
      float u_t = 0.f;
      #pragma unroll
      for (int p = 0; p < 16; ++p) u_t += __uint_as_float((u32)vv[p]);
      Sl[tid>>6][tid&63] = u_t;                                  // updates
      float sp;
      if (it == 0){
        const int d = tid & 63;
        sp = mu[d] + (fabsf(sigma[d]) + 1e-8f) * noise[batch*448 + tid];
      } else sp = Sst[tid>>6][tid&63];
      Qt[tid>>6][tid&63] = sp;                                   // slots_prev
    }
    __syncthreads();

    // ---- epilogue: GRU + LN + MLP (block-local, redundant per party) ----
    for (int o = tid; o < 2688; o += 1024){
      const int sl = o / 384, oo = o - sl*384;
      if (oo < 192){
        const float* wr = gwih + oo*64;
        float acc2 = gbih[oo];
        #pragma unroll
        for (int dd = 0; dd < 64; ++dd) acc2 += Sl[sl][dd]*wr[dd];
        Gx[sl][oo] = acc2;
      } else {
        const int o2 = oo - 192;
        const float* wr = gwhh + o2*64;
        float acc2 = gbhh[o2];
        #pragma unroll
        for (int dd = 0; dd < 64; ++dd) acc2 += Qt[sl][dd]*wr[dd];
        Gh[sl][o2] = acc2;
      }
    }
    __syncthreads();
    if (tid < 448){
      const int s = tid >> 6, d = tid & 63;
      float r = 1.f/(1.f + __expf(-(Gx[s][d] + Gh[s][d])));
      float z = 1.f/(1.f + __expf(-(Gx[s][64+d] + Gh[s][64+d])));
      float nn2 = tanhf(Gx[s][128+d] + r*Gh[s][128+d]);
      Qn[s][d] = (1.f - z)*nn2 + z*Qt[s][d];
    }
    __syncthreads();
    if (tid < 7){
      float m2 = 0.f;
      for (int d = 0; d < 64; ++d) m2 += Qn[tid][d];
      m2 *= (1.f/64.f);
      float v2 = 0.f;
      for (int d = 0; d < 64; ++d){ float dd = Qn[tid][d]-m2; v2 += dd*dd; }
      v2 *= (1.f/64.f);
      float rs2 = rsqrtf(v2 + 1e-5f);
      for (int d = 0; d < 64; ++d)
        Sl[tid][d] = (Qn[tid][d]-m2)*rs2*lnffg[d] + lnffb[d];
    }
    __syncthreads();
    if (tid < 896){
      const int s = tid >> 7, h = tid & 127;
      const float* f1 = fc1w + h*64;
      float acc2 = fc1b[h];
      #pragma unroll
      for (int d = 0; d < 64; ++d) acc2 += Sl[s][d]*f1[d];
      H1[s][h] = fmaxf(acc2, 0.f);
    }
    __syncthreads();
    if (tid < 448){
      const int s = tid >> 6, d = tid & 63;
      const float* f2 = fc2w + d*128;
      float o2 = fc2b[d];
      #pragma unroll
      for (int h = 0; h < 128; ++h) o2 += H1[s][h]*f2[h];
      float res = Qn[s][d] + o2;
      Sst[s][d] = res;
      if (it == 2 && party == 0) out[batch*448 + tid] = res;
    }
    __syncthreads();
  }
}

extern "C" void kernel_launch(void* const* d_in, const int* in_sizes, int n_in,
                              void* d_out, int out_size, void* d_ws, size_t ws_size,
                              hipStream_t stream)
{
  const float* inp   = (const float*)d_in[0];
  const float* noise = (const float*)d_in[1];
  const float* mu    = (const float*)d_in[2];
  const float* sigma = (const float*)d_in[3];
  const float* Wq    = (const float*)d_in[4];
  const float* Wk    = (const float*)d_in[5];
  const float* Wv    = (const float*)d_in[6];
  const float* gwih  = (const float*)d_in[7];
  const float* gwhh  = (const float*)d_in[8];
  const float* gbih  = (const float*)d_in[9];
  const float* gbhh  = (const float*)d_in[10];
  const float* fc1w  = (const float*)d_in[11];
  const float* fc1b  = (const float*)d_in[12];
  const float* fc2w  = (const float*)d_in[13];
  const float* fc2b  = (const float*)d_in[14];
  const float* lning = (const float*)d_in[15];
  const float* lninb = (const float*)d_in[16];
  const float* lnslg = (const float*)d_in[17];
  const float* lnslb = (const float*)d_in[18];
  const float* lnffg = (const float*)d_in[19];
  const float* lnffb = (const float*)d_in[20];
  const float* wiw   = (const float*)d_in[21];
  const float* wib   = (const float*)d_in[22];
  const float* wsw   = (const float*)d_in[23];
  const float* wsb   = (const float*)d_in[24];

  char* w = (char*)d_ws;
  u16*   knb     = (u16*)(w);                     // 33,554,432 B
  u16*   valb    = (u16*)(w + 33554432);          // 33,554,432 B
  float* lgA     = (float*)(w + 67108864);        // 1,048,576 B
  float* rnA     = (float*)(w + 68157440);        // 1,048,576 B
  float* lsePart = (float*)(w + 69206016);        // 2,048 B
  u64*   Tp      = (u64*)(w + 69208064);          // 2*2048*8 = 32,768 B
  u64*   upT     = (u64*)(w + 69240832);          // 256*448*8 = 917,504 B
  // total ws usage ~= 70.2 MB

  k_zero<<<116, 1024, 0, stream>>>(Tp);
  k_pre<<<256, 1024, 0, stream>>>(inp, Wk, Wv, lning, lninb, wiw, wib,
                                  knb, valb, lgA, rnA, lsePart);
  k_mesh<<<256, 1024, 0, stream>>>(noise, mu, sigma, Wq,
                                   gwih, gwhh, gbih, gbhh,
                                   fc1w, fc1b, fc2w, fc2b,
                                   lnslg, lnslb, lnffg, lnffb, wsw, wsb,
                                   knb, valb, lgA, rnA, lsePart,
                                   Tp, upT, (float*)d_out);
  (void)in_sizes; (void)n_in; (void)out_size; (void)ws_size;
}

// Round 6
// 2156.934 us; speedup vs baseline: 1.7803x; 1.7803x over previous
//
#include <hip/hip_runtime.h>

typedef unsigned int u32;
typedef unsigned short u16;
typedef unsigned long long u64;

#define NT 16384
#define LN7 1.9459101090932196f
#define ZWORDS 122880   // Tp 4096 + Tpf 4096 + upT 114688 u64 words

__device__ __forceinline__ u32 f2bf(float f){
  u32 u = __float_as_uint(f);
  return (u + 0x7fffu + ((u >> 16) & 1u)) >> 16;   // RNE to bf16
}
__device__ __forceinline__ float bflo(u32 v){ return __uint_as_float(v << 16); }

__global__ __launch_bounds__(1024) void k_zero(u64* p){
  int i = blockIdx.x * 1024 + threadIdx.x;
  if (i < ZWORDS) p[i] = 0ull;
}

// ---- sync primitives ----
// dev: device scope (proven rounds 0/3/4/5) — bypass L1+L2, coherent at MALL.
__device__ __forceinline__ void st_dev(u64* p, u64 v){
  asm volatile("global_store_dwordx2 %0, %1, off sc0 sc1" :: "v"(p), "v"(v) : "memory");
}
__device__ __forceinline__ u64 ld_dev(const u64* p){
  u64 v;
  asm volatile("global_load_dwordx2 %0, %1, off sc0 sc1\n\ts_waitcnt vmcnt(0)"
               : "=v"(v) : "v"(p) : "memory");
  return v;
}
// fast path: plain store写write-through to the storer's XCD L2; poll via L2
// atomic (atomics execute at L2, can never be served by a stale L1 line).
__device__ __forceinline__ void st_fast(u64* p, u64 v){
  asm volatile("global_store_dwordx2 %0, %1, off" :: "v"(p), "v"(v) : "memory");
}
__device__ __forceinline__ u64 atom_or0(u64* p){
  u64 r;
  asm volatile("global_atomic_or_x2 %0, %1, %2, off sc0\n\ts_waitcnt vmcnt(0)"
               : "=&v"(r) : "v"(p), "v"(0ull) : "memory");
  return r;
}
__device__ __forceinline__ u64 ld_issue(const u64* p){
  u64 v;
  asm volatile("global_load_dwordx2 %0, %1, off sc0 sc1" : "=v"(v) : "v"(p));
  return v;
}

// ============================================================================
// k_pre: 2048 blocks x 128 rows. Phase A: LN via 8-lane shfl (x8 regs only),
// normalized x -> LDS xs[128][68]. Phase B: 8 threads/row x 8 outputs each,
// scalar acc over float4 chunks (~50 live VGPR peak -> no spill at 64).
// ============================================================================
__global__ __launch_bounds__(1024) void k_pre(
    const float* __restrict__ inp,
    const float* __restrict__ Wk, const float* __restrict__ Wv,
    const float* __restrict__ lning, const float* __restrict__ lninb,
    const float* __restrict__ wiw, const float* __restrict__ wib,
    u16* __restrict__ knb, u16* __restrict__ valb,
    float* __restrict__ lgA, float* __restrict__ rnA,
    float* __restrict__ lsePart)
{
  const int tid = threadIdx.x, blk = blockIdx.x;
  const int batch = blk >> 7, chunk = blk & 127;
  const int r = tid >> 3, p = tid & 7, base8 = p << 3;
  const size_t row = ((size_t)batch << 14) + (size_t)((chunk << 7) | r);

  __shared__ float xs[128*68];
  __shared__ float red[16][2];

  // ---- Phase A: LN + wi logit, x -> LDS ----
  float lg;
  {
    float x8[8];
    const float4* xp = (const float4*)(inp + row*64 + base8);
    float4 a = xp[0], b = xp[1];
    x8[0]=a.x; x8[1]=a.y; x8[2]=a.z; x8[3]=a.w;
    x8[4]=b.x; x8[5]=b.y; x8[6]=b.z; x8[7]=b.w;
    float s1 = 0.f;
    #pragma unroll
    for (int i = 0; i < 8; ++i) s1 += x8[i];
    #pragma unroll
    for (int off = 1; off < 8; off <<= 1) s1 += __shfl_xor(s1, off, 64);
    const float mean = s1 * (1.f/64.f);
    float s2 = 0.f;
    #pragma unroll
    for (int i = 0; i < 8; ++i){ float d = x8[i]-mean; s2 += d*d; }
    #pragma unroll
    for (int off = 1; off < 8; off <<= 1) s2 += __shfl_xor(s2, off, 64);
    const float rstd = rsqrtf(s2*(1.f/64.f) + 1e-5f);
    float lgp = 0.f;
    #pragma unroll
    for (int i = 0; i < 8; ++i){
      x8[i] = (x8[i]-mean)*rstd*lning[base8+i] + lninb[base8+i];
      lgp += x8[i]*wiw[base8+i];
    }
    #pragma unroll
    for (int off = 1; off < 8; off <<= 1) lgp += __shfl_xor(lgp, off, 64);
    lg = lgp + wib[0];
    if (p == 0) lgA[row] = lg;
    float4* xd = (float4*)&xs[r*68 + base8];
    xd[0] = make_float4(x8[0],x8[1],x8[2],x8[3]);
    xd[1] = make_float4(x8[4],x8[5],x8[6],x8[7]);
  }
  // block LSE over 128 rows (leaders at p==0)
  {
    float m = (p == 0) ? lg : -3.4e38f;
    float s = (p == 0) ? 1.f : 0.f;
    #pragma unroll
    for (int off = 1; off < 64; off <<= 1){
      float om = __shfl_xor(m, off, 64);
      float os = __shfl_xor(s, off, 64);
      float nm = fmaxf(m, om);
      s = s*__expf(m-nm) + os*__expf(om-nm);
      m = nm;
    }
    if ((tid & 63) == 0){ red[tid>>6][0] = m; red[tid>>6][1] = s; }
  }
  __syncthreads();
  if (tid == 0){
    float M = red[0][0];
    for (int w = 1; w < 16; ++w) M = fmaxf(M, red[w][0]);
    float S = 0.f;
    for (int w = 0; w < 16; ++w) S += __expf(red[w][0]-M)*red[w][1];
    lsePart[blk*2+0] = M;
    lsePart[blk*2+1] = S;
  }

  // ---- Phase B: k/val GEMV from LDS x ----
  {
    const float4* xr = (const float4*)&xs[r*68];
    u32 kp[4], vp[4];
    float ss = 0.f;
    #pragma unroll
    for (int o = 0; o < 8; ++o){
      const float4* wk = (const float4*)(Wk + (base8+o)*64);
      const float4* wv = (const float4*)(Wv + (base8+o)*64);
      float acck = 0.f, accv = 0.f;
      #pragma unroll 2
      for (int c4 = 0; c4 < 16; ++c4){
        const float4 xv = xr[c4];
        const float4 wa = wk[c4];
        const float4 wb = wv[c4];
        acck += xv.x*wa.x + xv.y*wa.y + xv.z*wa.z + xv.w*wa.w;
        accv += xv.x*wb.x + xv.y*wb.y + xv.z*wb.z + xv.w*wb.w;
      }
      ss += acck*acck;
      if (o & 1){ kp[o>>1] |= f2bf(acck) << 16; vp[o>>1] |= f2bf(accv) << 16; }
      else      { kp[o>>1]  = f2bf(acck);       vp[o>>1]  = f2bf(accv); }
    }
    #pragma unroll
    for (int off = 1; off < 8; off <<= 1) ss += __shfl_xor(ss, off, 64);
    if (p == 0) rnA[row] = 1.f / fmaxf(sqrtf(ss), 1e-12f);
    *(uint4*)(knb + row*64 + base8) = *(uint4*)kp;
    *(uint4*)(valb + row*64 + base8) = *(uint4*)vp;
  }
}

// ============================================================================
// k_mesh: 256 blocks = 16 batches x 16 parties; 1 row/thread (fits 64 VGPR).
// Sync: leader double-stores {plain->local-L2 Tpf, device-scope Tp mirror};
// pollers try L2 atomics (bounded), fall back to proven device-scope spin.
// ============================================================================
__global__ __launch_bounds__(1024) void k_mesh(
    const float* __restrict__ noise, const float* __restrict__ mu,
    const float* __restrict__ sigma, const float* __restrict__ Wq,
    const float* __restrict__ gwih, const float* __restrict__ gwhh,
    const float* __restrict__ gbih, const float* __restrict__ gbhh,
    const float* __restrict__ fc1w, const float* __restrict__ fc1b,
    const float* __restrict__ fc2w, const float* __restrict__ fc2b,
    const float* __restrict__ lnslg, const float* __restrict__ lnslb,
    const float* __restrict__ lnffg, const float* __restrict__ lnffb,
    const float* __restrict__ wsw, const float* __restrict__ wsb,
    const u16* __restrict__ knb, const u16* __restrict__ valb,
    const float* __restrict__ lgA, const float* __restrict__ rnA,
    const float* __restrict__ lsePart,
    u64* Tp, u64* Tpf, u64* upT, float* out)
{
  const int tid = threadIdx.x;
  const int blk = blockIdx.x;
  // 16 parties of a batch share blk%8 -> same XCD under round-robin dispatch
  const int batch = (blk & 7) | ((blk >> 7) << 3);
  const int party = (blk >> 3) & 15;
  const int bp    = (batch << 4) | party;
  const int rbase = party << 10;

  __shared__ float Sl[7][64], Qn[7][64], Qt[7][64], Sst[7][64];
  __shared__ float Gx[7][192], Gh[7][192], H1[7][128];
  __shared__ float uacc[16][7][64];
  __shared__ float red[16][8];
  __shared__ float pol[16][8];
  __shared__ float vh[6][8], evT[6][8], logb[8], mxp[8], vw[8], rt[8];
  __shared__ float sS[2];

  float* ab = out + 7168 + (size_t)batch * 7 * NT;

  u32 bstep = 0;
  int tbuf = 0;
  int fastTries = 64, failcnt = 0;

  // mode 0: fwd step t; mode 1: G-sum; mode 2: bwd step t
  auto redshare = [&](float* part, int mode, int t){
    #pragma unroll
    for (int off = 32; off > 0; off >>= 1)
      #pragma unroll
      for (int s = 0; s < 7; ++s) part[s] += __shfl_xor(part[s], off, 64);
    if ((tid & 63) == 0){
      const int w = tid >> 6;
      #pragma unroll
      for (int s = 0; s < 7; ++s) red[w][s] = part[s];
    }
    __syncthreads();
    ++bstep;
    if (tid < 7){
      float p = 0.f;
      #pragma unroll
      for (int w = 0; w < 16; ++w) p += red[w][tid];
      u64 word = ((u64)bstep << 32) | (u64)__float_as_uint(p);
      st_fast(&Tpf[(tbuf << 11) + bp*8 + tid], word);
      st_dev (&Tp [(tbuf << 11) + bp*8 + tid], word);
    }
    if (tid < 128){
      const int w = tid >> 3, j0 = tid & 7;
      const int j = (j0 == 7) ? 0 : j0;
      u64* srcf = &Tpf[(tbuf << 11) + ((batch << 4) + w)*8 + j];
      const u64* srcd = &Tp[(tbuf << 11) + ((batch << 4) + w)*8 + j];
      u64 v; bool got = false;
      for (int k = 0; k < fastTries; ++k){
        v = atom_or0(srcf);
        if (__all((u32)(v >> 32) == bstep)){ got = true; break; }
      }
      if (!got){
        do { v = ld_dev(srcd); } while (!__all((u32)(v >> 32) == bstep));
        if (++failcnt >= 3) fastTries = 0;
      }
      if (j0 < 7) pol[w][j0] = __uint_as_float((u32)v);
    }
    __syncthreads();
    if (tid == 0){
      float T7[7];
      for (int s = 0; s < 7; ++s){
        float T = pol[0][s];
        for (int w = 1; w < 16; ++w) T += pol[w][s];
        T7[s] = T;
      }
      if (mode == 0){
        for (int s = 0; s < 7; ++s) vh[t][s] = logb[s] + mxp[t] - __logf(T7[s]);
        if (t < 5){
          float mxn = vh[t][0];
          for (int s = 1; s < 7; ++s) mxn = fmaxf(mxn, vh[t][s]);
          mxp[t+1] = mxn;
          for (int s = 0; s < 7; ++s) evT[t][s] = __expf(vh[t][s] - mxn);
        } else {
          for (int s = 0; s < 7; ++s) evT[5][s] = __expf(vh[5][s] - mxp[5]);
        }
      } else if (mode == 1){
        for (int s = 0; s < 7; ++s){
          vw[s] = T7[s] * __expf(vh[5][s] - logb[s] - mxp[5]);
          rt[s] = __expf(vh[4][s] - mxp[5]);
        }
      } else {
        for (int s = 0; s < 7; ++s){
          vw[s] = -T7[s] * __expf(vh[t-1][s] - logb[s] - mxp[t-1]);
          rt[s] = __expf(vh[t-2][s] - mxp[t-1]);
        }
      }
    }
    tbuf ^= 1;
    __syncthreads();
  };

  // ---- init: combine batch LSE (128 k_pre partials); per-row aR ----
  if (tid == 0){
    const float* lp = lsePart + batch*256;
    float M = lp[0];
    for (int w = 1; w < 128; ++w) M = fmaxf(M, lp[2*w]);
    float S = 0.f;
    for (int w = 0; w < 128; ++w) S += __expf(lp[2*w] - M) * lp[2*w + 1];
    sS[0] = M + __logf(S);
  }
  __syncthreads();
  const float LSE = sS[0];
  const size_t gr = ((size_t)batch << 14) | (size_t)(rbase | tid);
  const float aR = __expf(lgA[gr] - LSE + LN7);

  float ec[7], pb[7], rse5 = 0.f;

  for (int it = 0; it < 3; ++it){
    // ---- prologue: slots -> sn, logb, q, qn ----
    if (tid < 448){
      float sl;
      if (it == 0){
        const int d = tid & 63;
        sl = mu[d] + (fabsf(sigma[d]) + 1e-8f) * noise[batch*448 + tid];
      } else sl = Sst[tid>>6][tid&63];
      Sl[tid>>6][tid&63] = sl;
    }
    if (tid < 8) vh[5][tid] = 0.f;
    __syncthreads();
    if (tid < 7){
      float m2 = 0.f;
      for (int d = 0; d < 64; ++d) m2 += Sl[tid][d];
      m2 *= (1.f/64.f);
      float v2 = 0.f;
      for (int d = 0; d < 64; ++d){ float dd = Sl[tid][d]-m2; v2 += dd*dd; }
      v2 *= (1.f/64.f);
      float rs2 = rsqrtf(v2 + 1e-5f);
      float lgq = wsb[0];
      for (int d = 0; d < 64; ++d){
        float s = (Sl[tid][d]-m2)*rs2*lnslg[d] + lnslb[d];
        Qt[tid][d] = s;
        lgq += s*wsw[d];
      }
      red[0][tid] = lgq;
    }
    __syncthreads();
    if (tid == 0){
      float mx = red[0][0];
      for (int s = 1; s < 7; ++s) mx = fmaxf(mx, red[0][s]);
      float sm = 0.f;
      for (int s = 0; s < 7; ++s) sm += __expf(red[0][s]-mx);
      float lse = mx + __logf(sm);
      for (int s = 0; s < 7; ++s) logb[s] = red[0][s] - lse + LN7;
    }
    __syncthreads();
    if (tid < 448){
      const int s = tid >> 6, d = tid & 63;
      const float* wr = Wq + d*64;
      float acc2 = 0.f;
      #pragma unroll
      for (int dd = 0; dd < 64; ++dd) acc2 += Qt[s][dd]*wr[dd];
      Sl[s][d] = acc2;
    }
    __syncthreads();
    if (tid < 7){
      float sq = 0.f;
      for (int d = 0; d < 64; ++d) sq += Sl[tid][d]*Sl[tid][d];
      red[1][tid] = 1.f/fmaxf(sqrtf(sq), 1e-12f);
    }
    __syncthreads();
    if (tid < 448) Qn[tid>>6][tid&63] = Sl[tid>>6][tid&63]*red[1][tid>>6];
    __syncthreads();

    // ---- C build -> ec[s] = exp(-c), registers ----
    {
      float acc[7] = {0.f,0.f,0.f,0.f,0.f,0.f,0.f};
      const uint4* kr = (const uint4*)(knb + gr*64);
      #pragma unroll
      for (int q8 = 0; q8 < 8; ++q8){
        uint4 kv = kr[q8];
        float f0=bflo(kv.x), f1=__uint_as_float(kv.x & 0xffff0000u);
        float f2=bflo(kv.y), f3=__uint_as_float(kv.y & 0xffff0000u);
        float f4=bflo(kv.z), f5=__uint_as_float(kv.z & 0xffff0000u);
        float f6=bflo(kv.w), f7=__uint_as_float(kv.w & 0xffff0000u);
        const int d0 = q8*8;
        #pragma unroll
        for (int s = 0; s < 7; ++s){
          const float4 qa = *(const float4*)&Qn[s][d0];
          const float4 qb = *(const float4*)&Qn[s][d0+4];
          acc[s] += f0*qa.x + f1*qa.y + f2*qa.z + f3*qa.w
                  + f4*qb.x + f5*qb.y + f6*qb.z + f7*qb.w;
        }
      }
      const float rn_ = rnA[gr];
      #pragma unroll
      for (int s = 0; s < 7; ++s)
        ec[s] = __expf(-(1.f - rn_*acc[s]));
    }

    // ---- MESH: 4 grad passes (fwd5 + G + bwd5) + final fwd5 ----
    for (int m = 0; m < 5; ++m){
      if (tid == 0){
        float mxn = vh[5][0];
        for (int s = 1; s < 7; ++s) mxn = fmaxf(mxn, vh[5][s]);
        for (int s = 0; s < 7; ++s){ vh[0][s] = vh[5][s]; evT[0][s] = __expf(vh[5][s] - mxn); }
        mxp[1] = mxn;
      }
      __syncthreads();

      for (int t = 1; t <= 5; ++t){
        float evr[7];
        #pragma unroll
        for (int s = 0; s < 7; ++s) evr[s] = evT[t-1][s];
        float se = ec[0]*evr[0];
        #pragma unroll
        for (int s = 1; s < 7; ++s) se += ec[s]*evr[s];
        const float rse = 1.0f / se;
        if (t == 5) rse5 = rse;
        const float w = aR * rse;
        float t7[7];
        #pragma unroll
        for (int s = 0; s < 7; ++s) t7[s] = w * ec[s];
        redshare(t7, 0, t);
      }
      if (m == 4) break;

      // ---- G phase ----
      {
        const float mx5 = mxp[5];
        const float q = aR * rse5;
        const float base = __logf(aR) - mx5 + __logf(rse5);
        float gs[7];
        #pragma unroll
        for (int s = 0; s < 7; ++s){
          float at = q * ec[s] * evT[5][s];
          float lat = base + vh[5][s] + __logf(ec[s]);
          float G = -at * (lat + 1.f);
          pb[s] = G;
          gs[s] = G;
        }
        redshare(gs, 1, 0);
      }

      // ---- backward t = 5..1 ----
      for (int t = 5; t >= 1; --t){
        float vwr[7], rtr[7], evr[7];
        #pragma unroll
        for (int s = 0; s < 7; ++s){ vwr[s] = vw[s]; rtr[s] = rt[s]; evr[s] = evT[t-1][s]; }
        float se = ec[0]*evr[0];
        #pragma unroll
        for (int s = 1; s < 7; ++s) se += ec[s]*evr[s];
        const float rse = 1.0f / se;
        float ub = 0.f;
        if (t == 5){
          #pragma unroll
          for (int s = 0; s < 7; ++s) ub += pb[s];
        }
        float s1 = ec[0]*vwr[0];
        #pragma unroll
        for (int s = 1; s < 7; ++s) s1 += ec[s]*vwr[s];
        ub -= aR * rse * s1;
        const float u2 = ub * rse;
        const float ar_ = aR * rse;
        float ra[7];
        #pragma unroll
        for (int s = 0; s < 7; ++s){
          float er = ec[s] * rtr[s];
          ra[s] = u2 * er;
          pb[s] -= ar_ * vwr[s] * ec[s] + u2 * er;
        }
        if (t == 1){
          #pragma unroll
          for (int s = 0; s < 7; ++s) ec[s] = ec[s] * __expf(-pb[s]);   // c += pb
        }
        if (t > 1) redshare(ra, 2, t);
        else       __syncthreads();
      }
    } // m

    // ---- attn write ----
    {
      const int n = rbase | tid;
      const float wq = aR * rse5;
      #pragma unroll
      for (int s = 0; s < 7; ++s) ab[s*NT + n] = wq * ec[s] * evT[5][s];
    }
    __syncthreads();

    // ---- updates partial = attn^T @ val over this block's 1024 rows ----
    {
      const int w = tid >> 6, d = tid & 63;
      const int nb = rbase + (w << 6);
      float acc[7] = {0.f,0.f,0.f,0.f,0.f,0.f,0.f};
      const u16* vbp = valb + (((size_t)batch << 14) + (size_t)nb)*64 + d;
      #pragma unroll 1
      for (int i = 0; i < 64; i += 4){
        float4 a4[7];
        #pragma unroll
        for (int s = 0; s < 7; ++s) a4[s] = *(const float4*)(ab + s*NT + nb + i);
        #pragma unroll
        for (int j = 0; j < 4; ++j){
          float vv = bflo((u32)vbp[(size_t)(i+j)*64]);
          #pragma unroll
          for (int s = 0; s < 7; ++s) acc[s] += ((const float*)&a4[s])[j] * vv;
        }
      }
      #pragma unroll
      for (int s = 0; s < 7; ++s) uacc[w][s][d] = acc[s];
    }
    __syncthreads();

    // ---- cross-party sum of updates (16-party tagged sync, device scope) ----
    ++bstep;
    if (tid < 448){
      float u_ = 0.f;
      #pragma unroll
      for (int w = 0; w < 16; ++w) u_ += uacc[w][tid >> 6][tid & 63];
      u64 word = ((u64)bstep << 32) | (u64)__float_as_uint(u_);
      st_dev(&upT[(size_t)bp*448 + tid], word);
      const u64* base = &upT[(size_t)(batch << 4)*448 + tid];
      u64 vv[16];
      bool ok;
      do{
        #pragma unroll
        for (int p = 0; p < 16; ++p) vv[p] = ld_issue(base + p*448);
        asm volatile("s_waitcnt vmcnt(0)"
          : "+v"(vv[0]),"+v"(vv[1]),"+v"(vv[2]),"+v"(vv[3]),
            "+v"(vv[4]),"+v"(vv[5]),"+v"(vv[6]),"+v"(vv[7]),
            "+v"(vv[8]),"+v"(vv[9]),"+v"(vv[10]),"+v"(vv[11]),
            "+v"(vv[12]),"+v"(vv[13]),"+v"(vv[14]),"+v"(vv[15])
          :: "memory");
        ok = true;
        #pragma unroll
        for (int p = 0; p < 16; ++p) ok = ok && ((u32)(vv[p] >> 32) == bstep);
      } while (!__all(ok));
      float u_t = 0.f;
      #pragma unroll
      for (int p = 0; p < 16; ++p) u_t += __uint_as_float((u32)vv[p]);
      Sl[tid>>6][tid&63] = u_t;                                  // updates
      float sp;
      if (it == 0){
        const int d = tid & 63;
        sp = mu[d] + (fabsf(sigma[d]) + 1e-8f) * noise[batch*448 + tid];
      } else sp = Sst[tid>>6][tid&63];
      Qt[tid>>6][tid&63] = sp;                                   // slots_prev
    }
    __syncthreads();

    // ---- epilogue: GRU + LN + MLP (block-local, redundant per party) ----
    for (int o = tid; o < 2688; o += 1024){
      const int sl = o / 384, oo = o - sl*384;
      if (oo < 192){
        const float* wr = gwih + oo*64;
        float acc2 = gbih[oo];
        #pragma unroll
        for (int dd = 0; dd < 64; ++dd) acc2 += Sl[sl][dd]*wr[dd];
        Gx[sl][oo] = acc2;
      } else {
        const int o2 = oo - 192;
        const float* wr = gwhh + o2*64;
        float acc2 = gbhh[o2];
        #pragma unroll
        for (int dd = 0; dd < 64; ++dd) acc2 += Qt[sl][dd]*wr[dd];
        Gh[sl][o2] = acc2;
      }
    }
    __syncthreads();
    if (tid < 448){
      const int s = tid >> 6, d = tid & 63;
      float r = 1.f/(1.f + __expf(-(Gx[s][d] + Gh[s][d])));
      float z = 1.f/(1.f + __expf(-(Gx[s][64+d] + Gh[s][64+d])));
      float nn2 = tanhf(Gx[s][128+d] + r*Gh[s][128+d]);
      Qn[s][d] = (1.f - z)*nn2 + z*Qt[s][d];
    }
    __syncthreads();
    if (tid < 7){
      float m2 = 0.f;
      for (int d = 0; d < 64; ++d) m2 += Qn[tid][d];
      m2 *= (1.f/64.f);
      float v2 = 0.f;
      for (int d = 0; d < 64; ++d){ float dd = Qn[tid][d]-m2; v2 += dd*dd; }
      v2 *= (1.f/64.f);
      float rs2 = rsqrtf(v2 + 1e-5f);
      for (int d = 0; d < 64; ++d)
        Sl[tid][d] = (Qn[tid][d]-m2)*rs2*lnffg[d] + lnffb[d];
    }
    __syncthreads();
    if (tid < 896){
      const int s = tid >> 7, h = tid & 127;
      const float* f1 = fc1w + h*64;
      float acc2 = fc1b[h];
      #pragma unroll
      for (int d = 0; d < 64; ++d) acc2 += Sl[s][d]*f1[d];
      H1[s][h] = fmaxf(acc2, 0.f);
    }
    __syncthreads();
    if (tid < 448){
      const int s = tid >> 6, d = tid & 63;
      const float* f2 = fc2w + d*128;
      float o2 = fc2b[d];
      #pragma unroll
      for (int h = 0; h < 128; ++h) o2 += H1[s][h]*f2[h];
      float res = Qn[s][d] + o2;
      Sst[s][d] = res;
      if (it == 2 && party == 0) out[batch*448 + tid] = res;
    }
    __syncthreads();
  }
}

extern "C" void kernel_launch(void* const* d_in, const int* in_sizes, int n_in,
                              void* d_out, int out_size, void* d_ws, size_t ws_size,
                              hipStream_t stream)
{
  const float* inp   = (const float*)d_in[0];
  const float* noise = (const float*)d_in[1];
  const float* mu    = (const float*)d_in[2];
  const float* sigma = (const float*)d_in[3];
  const float* Wq    = (const float*)d_in[4];
  const float* Wk    = (const float*)d_in[5];
  const float* Wv    = (const float*)d_in[6];
  const float* gwih  = (const float*)d_in[7];
  const float* gwhh  = (const float*)d_in[8];
  const float* gbih  = (const float*)d_in[9];
  const float* gbhh  = (const float*)d_in[10];
  const float* fc1w  = (const float*)d_in[11];
  const float* fc1b  = (const float*)d_in[12];
  const float* fc2w  = (const float*)d_in[13];
  const float* fc2b  = (const float*)d_in[14];
  const float* lning = (const float*)d_in[15];
  const float* lninb = (const float*)d_in[16];
  const float* lnslg = (const float*)d_in[17];
  const float* lnslb = (const float*)d_in[18];
  const float* lnffg = (const float*)d_in[19];
  const float* lnffb = (const float*)d_in[20];
  const float* wiw   = (const float*)d_in[21];
  const float* wib   = (const float*)d_in[22];
  const float* wsw   = (const float*)d_in[23];
  const float* wsb   = (const float*)d_in[24];

  char* w = (char*)d_ws;
  u16*   knb     = (u16*)(w);                     // 33,554,432 B
  u16*   valb    = (u16*)(w + 33554432);          // 33,554,432 B
  float* lgA     = (float*)(w + 67108864);        // 1,048,576 B
  float* rnA     = (float*)(w + 68157440);        // 1,048,576 B
  float* lsePart = (float*)(w + 69206016);        // 2048*2*4 = 16,384 B
  u64*   Tp      = (u64*)(w + 69222400);          // 2*2048*8 = 32,768 B
  u64*   Tpf     = (u64*)(w + 69255168);          // 2*2048*8 = 32,768 B
  u64*   upT     = (u64*)(w + 69287936);          // 256*448*8 = 917,504 B
  // total ws usage ~= 70.2 MB

  k_zero<<<120, 1024, 0, stream>>>(Tp);
  k_pre<<<2048, 1024, 0, stream>>>(inp, Wk, Wv, lning, lninb, wiw, wib,
                                   knb, valb, lgA, rnA, lsePart);
  k_mesh<<<256, 1024, 0, stream>>>(noise, mu, sigma, Wq,
                                   gwih, gwhh, gbih, gbhh,
                                   fc1w, fc1b, fc2w, fc2b,
                                   lnslg, lnslb, lnffg, lnffb, wsw, wsb,
                                   knb, valb, lgA, rnA, lsePart,
                                   Tp, Tpf, upT, (float*)d_out);
  (void)in_sizes; (void)n_in; (void)out_size; (void)ws_size;
}

// Round 7
// 1209.607 us; speedup vs baseline: 3.1746x; 1.7832x over previous
//
#include <hip/hip_runtime.h>

typedef unsigned int u32;
typedef unsigned short u16;
typedef unsigned long long u64;

#define NT 16384
#define LN7 1.9459101090932196f
#define ZWORDS 118784   // Tp 4096 + upT 114688 u64 words

__device__ __forceinline__ u32 f2bf(float f){
  u32 u = __float_as_uint(f);
  return (u + 0x7fffu + ((u >> 16) & 1u)) >> 16;   // RNE to bf16
}
__device__ __forceinline__ float bflo(u32 v){ return __uint_as_float(v << 16); }

__global__ __launch_bounds__(1024) void k_zero(u64* p){
  int i = blockIdx.x * 1024 + threadIdx.x;
  if (i < ZWORDS) p[i] = 0ull;
}

// ---- sync primitives: pure device scope (proven rounds 0/4/5/6) ----
__device__ __forceinline__ void st_dev(u64* p, u64 v){
  asm volatile("global_store_dwordx2 %0, %1, off sc0 sc1" :: "v"(p), "v"(v) : "memory");
}
__device__ __forceinline__ void ld2_dev(const u64* p0, const u64* p1, u64& a, u64& b){
  asm volatile("global_load_dwordx2 %0, %2, off sc0 sc1\n\t"
               "global_load_dwordx2 %1, %3, off sc0 sc1\n\t"
               "s_waitcnt vmcnt(0)"
               : "=&v"(a), "=&v"(b) : "v"(p0), "v"(p1) : "memory");
}
__device__ __forceinline__ u64 ld_issue(const u64* p){
  u64 v;
  asm volatile("global_load_dwordx2 %0, %1, off sc0 sc1" : "=v"(v) : "v"(p));
  return v;
}

// ============================================================================
// k_pre: 2048 blocks x 128 rows. Phase A: LN via 8-lane shfl -> Xs (X^T) in
// LDS. Phase W: W'=[Wk;Wv] transposed into LDS. GEMM: 4x4 register tile per
// thread (16 FMA / 2 ds_read). ~40 VGPR peak.
// ============================================================================
__global__ __launch_bounds__(1024) void k_pre(
    const float* __restrict__ inp,
    const float* __restrict__ Wk, const float* __restrict__ Wv,
    const float* __restrict__ lning, const float* __restrict__ lninb,
    const float* __restrict__ wiw, const float* __restrict__ wib,
    u16* __restrict__ knb, u16* __restrict__ valb,
    float* __restrict__ lgA, float* __restrict__ rnA,
    float* __restrict__ lsePart)
{
  const int tid = threadIdx.x, blk = blockIdx.x;
  const int batch = blk >> 7, chunk = blk & 127;
  const size_t growbase = ((size_t)batch << 14) + ((size_t)chunk << 7);

  __shared__ float Xs[64*132];   // Xs[kk][row], stride 132
  __shared__ float Ws[64*132];   // Ws[kk][col], col<64 = Wk, col>=64 = Wv
  __shared__ float red[16][2];

  // ---- Phase A: LN per row (8 lanes/row), write X^T to LDS ----
  {
    const int r = tid >> 3, p = tid & 7, base8 = p << 3;
    const size_t row = growbase + r;
    float x8[8];
    const float4* xp = (const float4*)(inp + row*64 + base8);
    float4 a = xp[0], b = xp[1];
    x8[0]=a.x; x8[1]=a.y; x8[2]=a.z; x8[3]=a.w;
    x8[4]=b.x; x8[5]=b.y; x8[6]=b.z; x8[7]=b.w;
    float s1 = 0.f;
    #pragma unroll
    for (int i = 0; i < 8; ++i) s1 += x8[i];
    #pragma unroll
    for (int off = 1; off < 8; off <<= 1) s1 += __shfl_xor(s1, off, 64);
    const float mean = s1 * (1.f/64.f);
    float s2 = 0.f;
    #pragma unroll
    for (int i = 0; i < 8; ++i){ float d = x8[i]-mean; s2 += d*d; }
    #pragma unroll
    for (int off = 1; off < 8; off <<= 1) s2 += __shfl_xor(s2, off, 64);
    const float rstd = rsqrtf(s2*(1.f/64.f) + 1e-5f);
    float lgp = 0.f;
    #pragma unroll
    for (int i = 0; i < 8; ++i){
      float xv = (x8[i]-mean)*rstd*lning[base8+i] + lninb[base8+i];
      lgp += xv*wiw[base8+i];
      Xs[(base8+i)*132 + r] = xv;
    }
    #pragma unroll
    for (int off = 1; off < 8; off <<= 1) lgp += __shfl_xor(lgp, off, 64);
    const float lg = lgp + wib[0];
    if (p == 0) lgA[row] = lg;
    // wave-level LSE partial (leaders at p==0)
    float m = (p == 0) ? lg : -3.4e38f;
    float s = (p == 0) ? 1.f : 0.f;
    #pragma unroll
    for (int off = 1; off < 64; off <<= 1){
      float om = __shfl_xor(m, off, 64);
      float os = __shfl_xor(s, off, 64);
      float nm = fmaxf(m, om);
      s = s*__expf(m-nm) + os*__expf(om-nm);
      m = nm;
    }
    if ((tid & 63) == 0){ red[tid>>6][0] = m; red[tid>>6][1] = s; }
  }

  // ---- Phase W: stage W' transposed ----
  {
    const int c = tid >> 3, k0 = (tid & 7) << 3;
    const float* src = (c < 64) ? (Wk + c*64 + k0) : (Wv + (size_t)(c-64)*64 + k0);
    float4 w0 = *(const float4*)src;
    float4 w1 = *(const float4*)(src + 4);
    Ws[(k0+0)*132 + c] = w0.x; Ws[(k0+1)*132 + c] = w0.y;
    Ws[(k0+2)*132 + c] = w0.z; Ws[(k0+3)*132 + c] = w0.w;
    Ws[(k0+4)*132 + c] = w1.x; Ws[(k0+5)*132 + c] = w1.y;
    Ws[(k0+6)*132 + c] = w1.z; Ws[(k0+7)*132 + c] = w1.w;
  }
  __syncthreads();
  if (tid == 0){
    float M = red[0][0];
    for (int w = 1; w < 16; ++w) M = fmaxf(M, red[w][0]);
    float S = 0.f;
    for (int w = 0; w < 16; ++w) S += __expf(red[w][0]-M)*red[w][1];
    lsePart[blk*2+0] = M;
    lsePart[blk*2+1] = S;
  }

  // ---- GEMM: thread (tr,tc) computes rows 4tr..+3, cols 4tc..+3 ----
  const int tr = tid >> 5, tc = tid & 31;
  float acc[4][4] = {{0.f,0.f,0.f,0.f},{0.f,0.f,0.f,0.f},
                     {0.f,0.f,0.f,0.f},{0.f,0.f,0.f,0.f}};
  #pragma unroll 4
  for (int kk = 0; kk < 64; ++kk){
    float4 a4 = *(const float4*)&Xs[kk*132 + 4*tr];
    float4 b4 = *(const float4*)&Ws[kk*132 + 4*tc];
    float av[4] = {a4.x, a4.y, a4.z, a4.w};
    float bv[4] = {b4.x, b4.y, b4.z, b4.w};
    #pragma unroll
    for (int i = 0; i < 4; ++i)
      #pragma unroll
      for (int j = 0; j < 4; ++j) acc[i][j] += av[i]*bv[j];
  }

  // ---- epilogue: rn (k only), bf16 pack+store ----
  if (tc < 16){
    float ssq[4];
    #pragma unroll
    for (int i = 0; i < 4; ++i)
      ssq[i] = acc[i][0]*acc[i][0] + acc[i][1]*acc[i][1]
             + acc[i][2]*acc[i][2] + acc[i][3]*acc[i][3];
    #pragma unroll
    for (int off = 1; off < 16; off <<= 1)
      #pragma unroll
      for (int i = 0; i < 4; ++i) ssq[i] += __shfl_xor(ssq[i], off, 64);
    if (tc == 0){
      #pragma unroll
      for (int i = 0; i < 4; ++i)
        rnA[growbase + 4*tr + i] = 1.f/fmaxf(sqrtf(ssq[i]), 1e-12f);
    }
    #pragma unroll
    for (int i = 0; i < 4; ++i){
      u32 lo = f2bf(acc[i][0]) | (f2bf(acc[i][1]) << 16);
      u32 hi = f2bf(acc[i][2]) | (f2bf(acc[i][3]) << 16);
      *(uint2*)(knb + (growbase + 4*tr + i)*64 + 4*tc) = make_uint2(lo, hi);
    }
  } else {
    const int tcv = tc - 16;
    #pragma unroll
    for (int i = 0; i < 4; ++i){
      u32 lo = f2bf(acc[i][0]) | (f2bf(acc[i][1]) << 16);
      u32 hi = f2bf(acc[i][2]) | (f2bf(acc[i][3]) << 16);
      *(uint2*)(valb + (growbase + 4*tr + i)*64 + 4*tcv) = make_uint2(lo, hi);
    }
  }
}

// ============================================================================
// k_mesh: 256 blocks = 16 batches x 16 parties; 1024 rows/block.
// MESH (135 sync rounds) runs on WAVE 0 ONLY: per-row state in LDS (stride-9
// = bank-conflict-free), zero __syncthreads in the round loop, device-scope
// self-tagged protocol (proven). Other 15 waves park at one barrier.
// ============================================================================
__global__ __launch_bounds__(1024) void k_mesh(
    const float* __restrict__ noise, const float* __restrict__ mu,
    const float* __restrict__ sigma, const float* __restrict__ Wq,
    const float* __restrict__ gwih, const float* __restrict__ gwhh,
    const float* __restrict__ gbih, const float* __restrict__ gbhh,
    const float* __restrict__ fc1w, const float* __restrict__ fc1b,
    const float* __restrict__ fc2w, const float* __restrict__ fc2b,
    const float* __restrict__ lnslg, const float* __restrict__ lnslb,
    const float* __restrict__ lnffg, const float* __restrict__ lnffb,
    const float* __restrict__ wsw, const float* __restrict__ wsb,
    const u16* __restrict__ knb, const u16* __restrict__ valb,
    const float* __restrict__ lgA, const float* __restrict__ rnA,
    const float* __restrict__ lsePart,
    u64* Tp, u64* upT, float* out)
{
  const int tid = threadIdx.x;
  const int blk = blockIdx.x;
  const int batch = (blk & 7) | ((blk >> 7) << 3);
  const int party = (blk >> 3) & 15;
  const int bp    = (batch << 4) | party;
  const int rbase = party << 10;

  __shared__ float Sl[7][64], Qn[7][64], Qt[7][64], Sst[7][64];
  __shared__ float Gx[7][192], Gh[7][192], H1[7][128];
  __shared__ float uacc[16][7][64];
  __shared__ float red[16][8];
  __shared__ float vhL[6][8], logb[8], evT5L[8];
  __shared__ float polW[128];
  __shared__ float ecL[1024*9];
  __shared__ float pbL[1024*9];
  __shared__ float aRL[1024];
  __shared__ float rse5L[1024];
  __shared__ float sS[2];

  float* ab = out + 7168 + (size_t)batch * 7 * NT;

  u32 bstep = 0;     // wave-0 MESH tag counter (identical across blocks)
  int tbuf = 0;

  // ---- init: combine batch LSE (128 k_pre partials); per-row aR to LDS ----
  if (tid == 0){
    const float* lp = lsePart + batch*256;
    float M = lp[0];
    for (int w = 1; w < 128; ++w) M = fmaxf(M, lp[2*w]);
    float S = 0.f;
    for (int w = 0; w < 128; ++w) S += __expf(lp[2*w] - M) * lp[2*w + 1];
    sS[0] = M + __logf(S);
  }
  __syncthreads();
  const float LSE = sS[0];
  const size_t gr = ((size_t)batch << 14) | (size_t)(rbase | tid);
  aRL[tid] = __expf(lgA[gr] - LSE + LN7);

  for (int it = 0; it < 3; ++it){
    // ---- prologue: slots -> sn, logb, q, qn (as r6) ----
    if (tid < 448){
      float sl;
      if (it == 0){
        const int d = tid & 63;
        sl = mu[d] + (fabsf(sigma[d]) + 1e-8f) * noise[batch*448 + tid];
      } else sl = Sst[tid>>6][tid&63];
      Sl[tid>>6][tid&63] = sl;
    }
    if (tid < 8) vhL[5][tid] = 0.f;
    __syncthreads();
    if (tid < 7){
      float m2 = 0.f;
      for (int d = 0; d < 64; ++d) m2 += Sl[tid][d];
      m2 *= (1.f/64.f);
      float v2 = 0.f;
      for (int d = 0; d < 64; ++d){ float dd = Sl[tid][d]-m2; v2 += dd*dd; }
      v2 *= (1.f/64.f);
      float rs2 = rsqrtf(v2 + 1e-5f);
      float lgq = wsb[0];
      for (int d = 0; d < 64; ++d){
        float s = (Sl[tid][d]-m2)*rs2*lnslg[d] + lnslb[d];
        Qt[tid][d] = s;
        lgq += s*wsw[d];
      }
      red[0][tid] = lgq;
    }
    __syncthreads();
    if (tid == 0){
      float mx = red[0][0];
      for (int s = 1; s < 7; ++s) mx = fmaxf(mx, red[0][s]);
      float sm = 0.f;
      for (int s = 0; s < 7; ++s) sm += __expf(red[0][s]-mx);
      float lse = mx + __logf(sm);
      for (int s = 0; s < 7; ++s) logb[s] = red[0][s] - lse + LN7;
    }
    __syncthreads();
    if (tid < 448){
      const int s = tid >> 6, d = tid & 63;
      const float* wr = Wq + d*64;
      float acc2 = 0.f;
      #pragma unroll
      for (int dd = 0; dd < 64; ++dd) acc2 += Qt[s][dd]*wr[dd];
      Sl[s][d] = acc2;
    }
    __syncthreads();
    if (tid < 7){
      float sq = 0.f;
      for (int d = 0; d < 64; ++d) sq += Sl[tid][d]*Sl[tid][d];
      red[1][tid] = 1.f/fmaxf(sqrtf(sq), 1e-12f);
    }
    __syncthreads();
    if (tid < 448) Qn[tid>>6][tid&63] = Sl[tid>>6][tid&63]*red[1][tid>>6];
    __syncthreads();

    // ---- C build -> ecL[tid][s] = exp(-c) ----
    {
      float acc[7] = {0.f,0.f,0.f,0.f,0.f,0.f,0.f};
      const uint4* kr = (const uint4*)(knb + gr*64);
      #pragma unroll
      for (int q8 = 0; q8 < 8; ++q8){
        uint4 kv = kr[q8];
        float f0=bflo(kv.x), f1=__uint_as_float(kv.x & 0xffff0000u);
        float f2=bflo(kv.y), f3=__uint_as_float(kv.y & 0xffff0000u);
        float f4=bflo(kv.z), f5=__uint_as_float(kv.z & 0xffff0000u);
        float f6=bflo(kv.w), f7=__uint_as_float(kv.w & 0xffff0000u);
        const int d0 = q8*8;
        #pragma unroll
        for (int s = 0; s < 7; ++s){
          const float4 qa = *(const float4*)&Qn[s][d0];
          const float4 qb = *(const float4*)&Qn[s][d0+4];
          acc[s] += f0*qa.x + f1*qa.y + f2*qa.z + f3*qa.w
                  + f4*qb.x + f5*qb.y + f6*qb.z + f7*qb.w;
        }
      }
      const float rn_ = rnA[gr];
      #pragma unroll
      for (int s = 0; s < 7; ++s)
        ecL[tid*9+s] = __expf(-(1.f - rn_*acc[s]));
    }
    __syncthreads();

    // ================= WAVE-0 MESH (no intra-block barriers) =================
    if (tid < 64){
      const int lane = tid;
      float logb7[7];
      #pragma unroll
      for (int s = 0; s < 7; ++s) logb7[s] = logb[s];

      auto sync7 = [&](float (&part)[7], float (&T7)[7]){
        #pragma unroll
        for (int off = 32; off > 0; off >>= 1)
          #pragma unroll
          for (int s = 0; s < 7; ++s) part[s] += __shfl_xor(part[s], off, 64);
        ++bstep;
        float pv = part[0];
        pv = (lane==1)?part[1]:pv; pv = (lane==2)?part[2]:pv;
        pv = (lane==3)?part[3]:pv; pv = (lane==4)?part[4]:pv;
        pv = (lane==5)?part[5]:pv; pv = (lane==6)?part[6]:pv;
        if (lane < 7)
          st_dev(&Tp[(tbuf<<11) + bp*8 + lane],
                 ((u64)bstep << 32) | (u64)__float_as_uint(pv));
        const u64* base = &Tp[(tbuf<<11) + (size_t)(batch << 4)*8];
        const bool isPad = ((lane & 7) == 7);
        u64 v0, v1; bool ok;
        do {
          ld2_dev(base + lane, base + 64 + lane, v0, v1);
          ok = isPad || (((u32)(v0>>32) == bstep) && ((u32)(v1>>32) == bstep));
        } while (!__all(ok));
        polW[lane]      = __uint_as_float((u32)v0);
        polW[64 + lane] = __uint_as_float((u32)v1);
        #pragma unroll
        for (int s = 0; s < 7; ++s){
          float T = 0.f;
          #pragma unroll
          for (int w = 0; w < 16; ++w) T += polW[w*8+s];
          T7[s] = T;
        }
        tbuf ^= 1;
      };

      float ev[7], vwv[7], rtv[7];
      #pragma unroll 1
      for (int m = 0; m < 5; ++m){
        float mxp[6];
        {
          float v5[7];
          #pragma unroll
          for (int s = 0; s < 7; ++s) v5[s] = vhL[5][s];
          float mxn = v5[0];
          #pragma unroll
          for (int s = 1; s < 7; ++s) mxn = fmaxf(mxn, v5[s]);
          if (lane == 0){
            #pragma unroll
            for (int s = 0; s < 7; ++s) vhL[0][s] = v5[s];
          }
          mxp[1] = mxn;
          #pragma unroll
          for (int s = 0; s < 7; ++s) ev[s] = __expf(v5[s] - mxn);
        }
        // ---- fwd t=1..5 ----
        #pragma unroll
        for (int t = 1; t <= 5; ++t){
          float t7[7] = {0.f,0.f,0.f,0.f,0.f,0.f,0.f};
          #pragma unroll 2
          for (int rr = 0; rr < 16; ++rr){
            const int row = (rr << 6) | lane;
            float e[7];
            #pragma unroll
            for (int s = 0; s < 7; ++s) e[s] = ecL[row*9+s];
            const float aRr = aRL[row];
            float se = e[0]*ev[0];
            #pragma unroll
            for (int s = 1; s < 7; ++s) se += e[s]*ev[s];
            const float rse = 1.f/se;
            if (t == 5) rse5L[row] = rse;
            const float w = aRr*rse;
            #pragma unroll
            for (int s = 0; s < 7; ++s) t7[s] += w*e[s];
          }
          float T7[7];
          sync7(t7, T7);
          float vht[7];
          #pragma unroll
          for (int s = 0; s < 7; ++s) vht[s] = logb7[s] + mxp[t] - __logf(T7[s]);
          if (lane == 0){
            #pragma unroll
            for (int s = 0; s < 7; ++s) vhL[t][s] = vht[s];
          }
          if (t < 5){
            float mxn = vht[0];
            #pragma unroll
            for (int s = 1; s < 7; ++s) mxn = fmaxf(mxn, vht[s]);
            mxp[t+1] = mxn;
            #pragma unroll
            for (int s = 0; s < 7; ++s) ev[s] = __expf(vht[s] - mxn);
          } else {
            #pragma unroll
            for (int s = 0; s < 7; ++s) ev[s] = __expf(vht[s] - mxp[5]);
          }
        }
        if (m == 4) break;
        // ---- G phase ----
        {
          float vh5r[7];
          #pragma unroll
          for (int s = 0; s < 7; ++s) vh5r[s] = vhL[5][s];
          const float mx5 = mxp[5];
          float gs[7] = {0.f,0.f,0.f,0.f,0.f,0.f,0.f};
          #pragma unroll 2
          for (int rr = 0; rr < 16; ++rr){
            const int row = (rr << 6) | lane;
            float e[7];
            #pragma unroll
            for (int s = 0; s < 7; ++s) e[s] = ecL[row*9+s];
            const float aRr = aRL[row];
            const float r5 = rse5L[row];
            const float q = aRr*r5;
            const float basel = __logf(aRr) - mx5 + __logf(r5);
            #pragma unroll
            for (int s = 0; s < 7; ++s){
              float at = q * e[s] * ev[s];
              float lat = basel + vh5r[s] + __logf(e[s]);
              float G = -at * (lat + 1.f);
              pbL[row*9+s] = G;
              gs[s] += G;
            }
          }
          float T7[7];
          sync7(gs, T7);
          #pragma unroll
          for (int s = 0; s < 7; ++s){
            vwv[s] = T7[s] * __expf(vh5r[s] - logb7[s] - mxp[5]);
            rtv[s] = __expf(vhL[4][s] - mxp[5]);
          }
        }
        // ---- backward t=5..1 ----
        #pragma unroll
        for (int t = 5; t >= 1; --t){
          float evt[7];
          #pragma unroll
          for (int s = 0; s < 7; ++s) evt[s] = __expf(vhL[t-1][s] - mxp[t]);
          float ra[7] = {0.f,0.f,0.f,0.f,0.f,0.f,0.f};
          #pragma unroll 2
          for (int rr = 0; rr < 16; ++rr){
            const int row = (rr << 6) | lane;
            float e[7], pb[7];
            #pragma unroll
            for (int s = 0; s < 7; ++s) e[s] = ecL[row*9+s];
            #pragma unroll
            for (int s = 0; s < 7; ++s) pb[s] = pbL[row*9+s];
            const float aRr = aRL[row];
            float se = e[0]*evt[0];
            #pragma unroll
            for (int s = 1; s < 7; ++s) se += e[s]*evt[s];
            const float rse = 1.f/se;
            float ub = 0.f;
            if (t == 5){
              #pragma unroll
              for (int s = 0; s < 7; ++s) ub += pb[s];
            }
            float s1 = e[0]*vwv[0];
            #pragma unroll
            for (int s = 1; s < 7; ++s) s1 += e[s]*vwv[s];
            ub -= aRr * rse * s1;
            const float u2 = ub * rse;
            const float ar_ = aRr * rse;
            #pragma unroll
            for (int s = 0; s < 7; ++s){
              float er = e[s] * rtv[s];
              ra[s] += u2 * er;
              pb[s] -= ar_ * vwv[s] * e[s] + u2 * er;
            }
            if (t > 1){
              #pragma unroll
              for (int s = 0; s < 7; ++s) pbL[row*9+s] = pb[s];
            } else {
              #pragma unroll
              for (int s = 0; s < 7; ++s) ecL[row*9+s] = e[s] * __expf(-pb[s]);
            }
          }
          if (t > 1){
            float T7[7];
            sync7(ra, T7);
            #pragma unroll
            for (int s = 0; s < 7; ++s){
              vwv[s] = -T7[s] * __expf(vhL[t-1][s] - logb7[s] - mxp[t-1]);
              rtv[s] = __expf(vhL[t-2][s] - mxp[t-1]);
            }
          }
        }
      } // m
      if (lane == 0){
        #pragma unroll
        for (int s = 0; s < 7; ++s) evT5L[s] = ev[s];
      }
    }
    __syncthreads();
    // =========================================================================

    // ---- attn write ----
    {
      const int n = rbase | tid;
      const float wq = aRL[tid] * rse5L[tid];
      #pragma unroll
      for (int s = 0; s < 7; ++s) ab[s*NT + n] = wq * ecL[tid*9+s] * evT5L[s];
    }
    __syncthreads();

    // ---- updates partial = attn^T @ val over this block's 1024 rows ----
    {
      const int w = tid >> 6, d = tid & 63;
      const int nb = rbase + (w << 6);
      float acc[7] = {0.f,0.f,0.f,0.f,0.f,0.f,0.f};
      const u16* vbp = valb + (((size_t)batch << 14) + (size_t)nb)*64 + d;
      #pragma unroll 1
      for (int i = 0; i < 64; i += 4){
        float4 a4[7];
        #pragma unroll
        for (int s = 0; s < 7; ++s) a4[s] = *(const float4*)(ab + s*NT + nb + i);
        #pragma unroll
        for (int j = 0; j < 4; ++j){
          float vv = bflo((u32)vbp[(size_t)(i+j)*64]);
          #pragma unroll
          for (int s = 0; s < 7; ++s) acc[s] += ((const float*)&a4[s])[j] * vv;
        }
      }
      #pragma unroll
      for (int s = 0; s < 7; ++s) uacc[w][s][d] = acc[s];
    }
    __syncthreads();

    // ---- cross-party sum of updates (16-party tagged sync, tag = it+1) ----
    {
      const u32 utag = (u32)(it + 1);
      if (tid < 448){
        float u_ = 0.f;
        #pragma unroll
        for (int w = 0; w < 16; ++w) u_ += uacc[w][tid >> 6][tid & 63];
        st_dev(&upT[(size_t)bp*448 + tid],
               ((u64)utag << 32) | (u64)__float_as_uint(u_));
        const u64* base = &upT[(size_t)(batch << 4)*448 + tid];
        u64 vv[16];
        bool ok;
        do{
          #pragma unroll
          for (int p = 0; p < 16; ++p) vv[p] = ld_issue(base + p*448);
          asm volatile("s_waitcnt vmcnt(0)"
            : "+v"(vv[0]),"+v"(vv[1]),"+v"(vv[2]),"+v"(vv[3]),
              "+v"(vv[4]),"+v"(vv[5]),"+v"(vv[6]),"+v"(vv[7]),
              "+v"(vv[8]),"+v"(vv[9]),"+v"(vv[10]),"+v"(vv[11]),
              "+v"(vv[12]),"+v"(vv[13]),"+v"(vv[14]),"+v"(vv[15])
            :: "memory");
          ok = true;
          #pragma unroll
          for (int p = 0; p < 16; ++p) ok = ok && ((u32)(vv[p] >> 32) == utag);
        } while (!__all(ok));
        float u_t = 0.f;
        #pragma unroll
        for (int p = 0; p < 16; ++p) u_t += __uint_as_float((u32)vv[p]);
        Sl[tid>>6][tid&63] = u_t;                                  // updates
        float sp;
        if (it == 0){
          const int d = tid & 63;
          sp = mu[d] + (fabsf(sigma[d]) + 1e-8f) * noise[batch*448 + tid];
        } else sp = Sst[tid>>6][tid&63];
        Qt[tid>>6][tid&63] = sp;                                   // slots_prev
      }
    }
    __syncthreads();

    // ---- epilogue: GRU + LN + MLP (block-local, redundant per party) ----
    for (int o = tid; o < 2688; o += 1024){
      const int sl = o / 384, oo = o - sl*384;
      if (oo < 192){
        const float* wr = gwih + oo*64;
        float acc2 = gbih[oo];
        #pragma unroll
        for (int dd = 0; dd < 64; ++dd) acc2 += Sl[sl][dd]*wr[dd];
        Gx[sl][oo] = acc2;
      } else {
        const int o2 = oo - 192;
        const float* wr = gwhh + o2*64;
        float acc2 = gbhh[o2];
        #pragma unroll
        for (int dd = 0; dd < 64; ++dd) acc2 += Qt[sl][dd]*wr[dd];
        Gh[sl][o2] = acc2;
      }
    }
    __syncthreads();
    if (tid < 448){
      const int s = tid >> 6, d = tid & 63;
      float r = 1.f/(1.f + __expf(-(Gx[s][d] + Gh[s][d])));
      float z = 1.f/(1.f + __expf(-(Gx[s][64+d] + Gh[s][64+d])));
      float nn2 = tanhf(Gx[s][128+d] + r*Gh[s][128+d]);
      Qn[s][d] = (1.f - z)*nn2 + z*Qt[s][d];
    }
    __syncthreads();
    if (tid < 7){
      float m2 = 0.f;
      for (int d = 0; d < 64; ++d) m2 += Qn[tid][d];
      m2 *= (1.f/64.f);
      float v2 = 0.f;
      for (int d = 0; d < 64; ++d){ float dd = Qn[tid][d]-m2; v2 += dd*dd; }
      v2 *= (1.f/64.f);
      float rs2 = rsqrtf(v2 + 1e-5f);
      for (int d = 0; d < 64; ++d)
        Sl[tid][d] = (Qn[tid][d]-m2)*rs2*lnffg[d] + lnffb[d];
    }
    __syncthreads();
    if (tid < 896){
      const int s = tid >> 7, h = tid & 127;
      const float* f1 = fc1w + h*64;
      float acc2 = fc1b[h];
      #pragma unroll
      for (int d = 0; d < 64; ++d) acc2 += Sl[s][d]*f1[d];
      H1[s][h] = fmaxf(acc2, 0.f);
    }
    __syncthreads();
    if (tid < 448){
      const int s = tid >> 6, d = tid & 63;
      const float* f2 = fc2w + d*128;
      float o2 = fc2b[d];
      #pragma unroll
      for (int h = 0; h < 128; ++h) o2 += H1[s][h]*f2[h];
      float res = Qn[s][d] + o2;
      Sst[s][d] = res;
      if (it == 2 && party == 0) out[batch*448 + tid] = res;
    }
    __syncthreads();
  }
}

extern "C" void kernel_launch(void* const* d_in, const int* in_sizes, int n_in,
                              void* d_out, int out_size, void* d_ws, size_t ws_size,
                              hipStream_t stream)
{
  const float* inp   = (const float*)d_in[0];
  const float* noise = (const float*)d_in[1];
  const float* mu    = (const float*)d_in[2];
  const float* sigma = (const float*)d_in[3];
  const float* Wq    = (const float*)d_in[4];
  const float* Wk    = (const float*)d_in[5];
  const float* Wv    = (const float*)d_in[6];
  const float* gwih  = (const float*)d_in[7];
  const float* gwhh  = (const float*)d_in[8];
  const float* gbih  = (const float*)d_in[9];
  const float* gbhh  = (const float*)d_in[10];
  const float* fc1w  = (const float*)d_in[11];
  const float* fc1b  = (const float*)d_in[12];
  const float* fc2w  = (const float*)d_in[13];
  const float* fc2b  = (const float*)d_in[14];
  const float* lning = (const float*)d_in[15];
  const float* lninb = (const float*)d_in[16];
  const float* lnslg = (const float*)d_in[17];
  const float* lnslb = (const float*)d_in[18];
  const float* lnffg = (const float*)d_in[19];
  const float* lnffb = (const float*)d_in[20];
  const float* wiw   = (const float*)d_in[21];
  const float* wib   = (const float*)d_in[22];
  const float* wsw   = (const float*)d_in[23];
  const float* wsb   = (const float*)d_in[24];

  char* w = (char*)d_ws;
  u16*   knb     = (u16*)(w);                     // 33,554,432 B
  u16*   valb    = (u16*)(w + 33554432);          // 33,554,432 B
  float* lgA     = (float*)(w + 67108864);        // 1,048,576 B
  float* rnA     = (float*)(w + 68157440);        // 1,048,576 B
  float* lsePart = (float*)(w + 69206016);        // 2048*2*4 = 16,384 B
  u64*   Tp      = (u64*)(w + 69222400);          // 2*2048*8 = 32,768 B
  u64*   upT     = (u64*)(w + 69255168);          // 256*448*8 = 917,504 B
  // total ws usage ~= 70.2 MB

  k_zero<<<116, 1024, 0, stream>>>(Tp);
  k_pre<<<2048, 1024, 0, stream>>>(inp, Wk, Wv, lning, lninb, wiw, wib,
                                   knb, valb, lgA, rnA, lsePart);
  k_mesh<<<256, 1024, 0, stream>>>(noise, mu, sigma, Wq,
                                   gwih, gwhh, gbih, gbhh,
                                   fc1w, fc1b, fc2w, fc2b,
                                   lnslg, lnslb, lnffg, lnffb, wsw, wsb,
                                   knb, valb, lgA, rnA, lsePart,
                                   Tp, upT, (float*)d_out);
  (void)in_sizes; (void)n_in; (void)out_size; (void)ws_size;
}